// Round 7
// baseline (223.240 us; speedup 1.0000x reference)
//
#include <hip/hip_runtime.h>

#define BATCH 2048
#define T     128
#define CIN   2
#define COUT  16
#define H     232
#define RPB   8                 // batch rows per block
#define NBLK  (BATCH/RPB)       // 256 blocks -> 1 per CU
#define NTHR  512               // 8 waves, 2/SIMD
#define NGRP  15                // j-groups of 16 (232 -> 240 padded)
#define NT2   48                // tiles: r=0..14, z=15..29, n=30..44, 45..47 zero pad
#define NS    9                 // K slices of 32
#define HROW  272               // h row stride in halves
#define HBUF_H (RPB * HROW)     // 2176 halves per ping-pong h buffer

// dynamic LDS carve (bytes)
#define OFF_HA   0
#define SZ_HA    (2 * RPB * HROW * 2)          // 8704: ping-pong fp16 h
#define OFF_XE   (OFF_HA + SZ_HA)
#define SZ_XE    (T * RPB * 16 * 2)            // 32768: conv output all t
#define OFF_WL   (OFF_XE + SZ_XE)
#define SZ_WL    (8 * 10 * 64 * 8 * 2)         // 81920: per-wave z s0-3 x2 + xn x2
#define OFF_CW   (OFF_WL + SZ_WL)
#define SZ_CW    512
#define SMEM_BYTES (OFF_CW + SZ_CW)            // 123904
#define OFF_XE_H (OFF_XE / 2)

#define L2E     1.4426950408889634f
#define TWO_L2E 2.8853900817779268f

typedef _Float16 half8 __attribute__((ext_vector_type(8)));
typedef float  floatx4 __attribute__((ext_vector_type(4)));

#define MFMA __builtin_amdgcn_mfma_f32_16x16x32_f16
#define PRIO(n) __builtin_amdgcn_s_setprio(n)

// packed fp16 weights, fragment-contiguous: [tile][slice][lane][8]
__device__ __align__(16) _Float16 g_packedW[NT2 * NS * 64 * 8];

__global__ void pack_w_kernel(const float* __restrict__ w_ih,
                              const float* __restrict__ w_hh) {
  int tile = blockIdx.x, slice = blockIdx.y, lane = threadIdx.x;
  int grp = tile / NGRP;                       // 0=r,1=z,2=n (3=dummy)
  int j   = (tile % NGRP) * 16 + (lane & 15);
  int g   = grp * H + j;
  bool valid = (tile < 3 * NGRP) && (j < H);
  half8 v = {};
  if (valid) {
#pragma unroll
    for (int i = 0; i < 8; ++i) {
      int k = slice * 32 + ((lane >> 4) << 3) + i;
      float f = 0.f;
      if (slice < 8) {
        if (k < H) f = w_hh[g * H + k];
        else if (k < H + COUT && grp < 2) f = w_ih[g * COUT + (k - H)];
      } else {
        int xk = k - 256;
        if (xk >= 0 && xk < COUT && grp == 2) f = w_ih[g * COUT + xk];
      }
      v[i] = (_Float16)f;
    }
  }
  *(half8*)&g_packedW[((tile * NS + slice) * 64 + lane) * 8] = v;
}

__global__ __launch_bounds__(NTHR, 2) void st_gru_kernel(
    const float* __restrict__ X,
    const float* __restrict__ conv_w, const float* __restrict__ conv_b,
    const float* __restrict__ b_ih, const float* __restrict__ b_hh,
    float* __restrict__ out) {

  extern __shared__ __align__(16) char smem[];
  _Float16* lds16  = (_Float16*)smem;
  _Float16* hAflat = (_Float16*)(smem + OFF_HA);
  _Float16* Xemb   = (_Float16*)(smem + OFF_XE);
  _Float16* wLDS   = (_Float16*)(smem + OFF_WL);
  float*    cwp    = (float*)(smem + OFF_CW);

  const int tid  = threadIdx.x;
  const int lane = tid & 63;
  const int wave = tid >> 6;
  const int r_a  = lane & 15;   // A row / C col (gate j within group)
  const int ch4  = lane >> 4;   // k-chunk / C row group
  const int blk  = blockIdx.x;
  const int rr   = r_a & 7;     // batch row this lane reads (rows 8-15 duplicate 0-7)
  const int swz  = rr & 3;

  for (int i = tid; i < 2 * RPB * HROW; i += NTHR) hAflat[i] = (_Float16)0;
  if (tid < COUT * CIN * 3) cwp[tid] = conv_w[tid];
  if (tid < COUT) cwp[96 + tid] = conv_b[tid];
  __syncthreads();

  // ---- conv1d(2->16,k=3,pad=1)+ReLU for ALL t upfront -> Xemb (fp16)
  for (int p = tid; p < RPB * T; p += NTHR) {
    int r = p >> 7, t = p & (T - 1);
    const float* xr = X + (size_t)(blk * RPB + r) * (T * CIN);
    float x0[3], x1[3];
#pragma unroll
    for (int d = 0; d < 3; ++d) {
      int tt = t + d - 1;
      bool ok = (unsigned)tt < (unsigned)T;
      x0[d] = ok ? xr[tt * 2] : 0.f;
      x1[d] = ok ? xr[tt * 2 + 1] : 0.f;
    }
    half8 lo, hi;
#pragma unroll
    for (int c = 0; c < COUT; ++c) {
      float a = cwp[96 + c];
#pragma unroll
      for (int d = 0; d < 3; ++d)
        a += x0[d] * cwp[c * 6 + d] + x1[d] * cwp[c * 6 + 3 + d];
      _Float16 hv = (_Float16)fmaxf(a, 0.f);
      if (c < 8) lo[c] = hv; else hi[c - 8] = hv;
    }
    *(half8*)&Xemb[(t * RPB + r) * 16] = lo;
    *(half8*)&Xemb[(t * RPB + r) * 16 + 8] = hi;
  }

  // ---- per-wave tiles (2 gate-triples each; wave 7's 2nd is pad -> skipped)
  const int gi0 = wave * 2, gi1 = wave * 2 + 1;
  const bool g1ok = (gi1 < NGRP);
  const int tr0 = gi0, tz0 = gi0 + NGRP, tn0 = gi0 + 2 * NGRP;
  const int tr1 = g1ok ? gi1 : 45, tz1 = g1ok ? gi1 + NGRP : 46, tn1 = g1ok ? gi1 + 2 * NGRP : 47;
  const half8* Wp = (const half8*)g_packedW;

  // LDS-staged frags (10/wave): [0-3]=z0 s0-3, [4-7]=z1 s0-3, [8]=xn0, [9]=xn1
  half8* myz = (half8*)(wLDS + wave * (10 * 64 * 8));
#pragma unroll
  for (int f = 0; f < 4; ++f) myz[f * 64 + lane] = Wp[(tz0 * NS + f) * 64 + lane];
#pragma unroll
  for (int f = 0; f < 4; ++f) myz[(4 + f) * 64 + lane] = Wp[(tz1 * NS + f) * 64 + lane];
  myz[8 * 64 + lane] = Wp[(tn0 * NS + 8) * 64 + lane];
  myz[9 * 64 + lane] = Wp[(tn1 * NS + 8) * 64 + lane];

  // VGPR/AGPR-resident frags: r s0-7, n s0-7, z s4-7 (R4 config)
  half8 wr0[8], wr1[8], wn0[8], wn1[8], wzh0[4], wzh1[4];
#pragma unroll
  for (int s = 0; s < 8; ++s) {
    wr0[s] = Wp[(tr0 * NS + s) * 64 + lane];
    wr1[s] = Wp[(tr1 * NS + s) * 64 + lane];
    wn0[s] = Wp[(tn0 * NS + s) * 64 + lane];
    wn1[s] = Wp[(tn1 * NS + s) * 64 + lane];
  }
#pragma unroll
  for (int s = 0; s < 4; ++s) {
    wzh0[s] = Wp[(tz0 * NS + 4 + s) * 64 + lane];
    wzh1[s] = Wp[(tz1 * NS + 4 + s) * 64 + lane];
  }

  const int j0 = gi0 * 16 + r_a, j1 = gi1 * 16 + r_a;
  // pre-scaled biases for exp2-folded sigmoids
  float nbsr0 = 0.f, nbsz0 = 0.f, bin0 = 0.f, bhn0 = 0.f;
  float nbsr1 = 0.f, nbsz1 = 0.f, bin1 = 0.f, bhn1 = 0.f;
  if (j0 < H) {
    nbsr0 = -L2E * (b_ih[j0] + b_hh[j0]);
    nbsz0 = -L2E * (b_ih[H + j0] + b_hh[H + j0]);
    bin0 = b_ih[2 * H + j0]; bhn0 = b_hh[2 * H + j0];
  }
  if (g1ok && j1 < H) {
    nbsr1 = -L2E * (b_ih[j1] + b_hh[j1]);
    nbsz1 = -L2E * (b_ih[H + j1] + b_hh[H + j1]);
    bin1 = b_ih[2 * H + j1]; bhn1 = b_hh[2 * H + j1];
  }

  // all-lane update distribution: ch4 -> (elem base, row base)
  const int eb   = (ch4 & 2);
  const int rowb = ((ch4 & 1) << 2) | (ch4 & 2);

  int woff0[2], woff1[2];
#pragma unroll
  for (int u = 0; u < 2; ++u) {
    int row = rowb + u;
    woff0[u] = row * HROW + ((j0 & ~31) | ((((j0 >> 3) & 3) ^ (row & 3)) << 3) | (j0 & 7));
    woff1[u] = row * HROW + ((j1 & ~31) | ((((j1 >> 3) & 3) ^ (row & 3)) << 3) | (j1 & 7));
  }

  float h0[2] = {0.f, 0.f};
  float h1[2] = {0.f, 0.f};

  // loop-invariant LDS half-indices
  const int aoff = rr * HROW + ((ch4 ^ swz) << 3);
  const int inc7 = (ch4 == 0) ? 0 : 256;
  int pa7_e = (ch4 == 0) ? (0      + rr * HROW + 224 + (swz << 3))
                         : (OFF_XE_H + rr * 16 + ((ch4 == 2) ? 8 : 0));
  int pa7_o = (ch4 == 0) ? (HBUF_H + rr * HROW + 224 + (swz << 3))
                         : (OFF_XE_H + 128 + rr * 16 + ((ch4 == 2) ? 8 : 0));
  int a8i = OFF_XE_H + rr * 16 + ((ch4 & 1) << 3);

  __syncthreads();

  // R4 schedule + wave7 skip + setprio + exp2 activations. No sched_barriers.
#define GRU_STEP(RBH, WBH, PA7, A8I) do {                                      \
    half8 A_[7];                                                               \
    _Pragma("unroll")                                                          \
    for (int s = 0; s < 7; ++s)                                                \
      A_[s] = *(const half8*)&lds16[(RBH) + aoff + s * 32];                    \
    half8 A7_ = *(const half8*)&lds16[(PA7)];                                  \
    half8 A8_ = *(const half8*)&lds16[(A8I)];                                  \
    PRIO(1);                                                                   \
    /* ---- triple 0: 25 MFMAs (R4 order: per-slice r,z,n) ---- */             \
    floatx4 ra0 = {}, za0 = {}, na0 = {}, xa0 = {};                            \
    _Pragma("unroll")                                                          \
    for (int s = 0; s < 4; ++s) {                                              \
      ra0 = MFMA(A_[s], wr0[s], ra0, 0, 0, 0);                                 \
      za0 = MFMA(A_[s], myz[s * 64 + lane], za0, 0, 0, 0);                     \
      na0 = MFMA(A_[s], wn0[s], na0, 0, 0, 0);                                 \
    }                                                                          \
    _Pragma("unroll")                                                          \
    for (int s = 4; s < 7; ++s) {                                              \
      ra0 = MFMA(A_[s], wr0[s], ra0, 0, 0, 0);                                 \
      za0 = MFMA(A_[s], wzh0[s - 4], za0, 0, 0, 0);                            \
      na0 = MFMA(A_[s], wn0[s], na0, 0, 0, 0);                                 \
    }                                                                          \
    ra0 = MFMA(A7_, wr0[7], ra0, 0, 0, 0);                                     \
    za0 = MFMA(A7_, wzh0[3], za0, 0, 0, 0);                                    \
    na0 = MFMA(A7_, wn0[7], na0, 0, 0, 0);                                     \
    xa0 = MFMA(A8_, myz[8 * 64 + lane], xa0, 0, 0, 0);                         \
    if (g1ok) {                                                                \
      /* ---- triple 1 s0-3 (12 MFMAs) ---- */                                 \
      floatx4 ra1 = {}, za1 = {}, na1 = {}, xa1 = {};                          \
      _Pragma("unroll")                                                        \
      for (int s = 0; s < 4; ++s) {                                            \
        ra1 = MFMA(A_[s], wr1[s], ra1, 0, 0, 0);                               \
        za1 = MFMA(A_[s], myz[(4 + s) * 64 + lane], za1, 0, 0, 0);             \
        na1 = MFMA(A_[s], wn1[s], na1, 0, 0, 0);                               \
      }                                                                        \
      PRIO(0);                                                                 \
      /* sigmoids of triple 0 (overlap triple-1 MFMA stream) */                \
      float sr_[2], sz_[2];                                                    \
      _Pragma("unroll")                                                        \
      for (int u = 0; u < 2; ++u) {                                            \
        sr_[u] = __builtin_amdgcn_rcpf(                                        \
            1.f + __builtin_amdgcn_exp2f(fmaf(ra0[eb + u], -L2E, nbsr0)));     \
        sz_[u] = __builtin_amdgcn_rcpf(                                        \
            1.f + __builtin_amdgcn_exp2f(fmaf(za0[eb + u], -L2E, nbsz0)));     \
      }                                                                        \
      PRIO(1);                                                                 \
      _Pragma("unroll")                                                        \
      for (int s = 4; s < 7; ++s) {                                            \
        ra1 = MFMA(A_[s], wr1[s], ra1, 0, 0, 0);                               \
        za1 = MFMA(A_[s], wzh1[s - 4], za1, 0, 0, 0);                          \
        na1 = MFMA(A_[s], wn1[s], na1, 0, 0, 0);                               \
      }                                                                        \
      PRIO(0);                                                                 \
      /* update 0 (overlaps triple-1 tail) */                                  \
      _Pragma("unroll")                                                        \
      for (int u = 0; u < 2; ++u) {                                            \
        float pre = fmaf(sr_[u], na0[eb + u] + bhn0, xa0[eb + u] + bin0);      \
        float e2 = __builtin_amdgcn_exp2f(pre * TWO_L2E);                      \
        float n = fmaf(-2.f, __builtin_amdgcn_rcpf(e2 + 1.f), 1.f);            \
        h0[u] = fmaf(sz_[u], h0[u] - n, n);                                    \
        lds16[(WBH) + woff0[u]] = (_Float16)h0[u];                             \
      }                                                                        \
      PRIO(1);                                                                 \
      ra1 = MFMA(A7_, wr1[7], ra1, 0, 0, 0);                                   \
      za1 = MFMA(A7_, wzh1[3], za1, 0, 0, 0);                                  \
      na1 = MFMA(A7_, wn1[7], na1, 0, 0, 0);                                   \
      xa1 = MFMA(A8_, myz[9 * 64 + lane], xa1, 0, 0, 0);                       \
      PRIO(0);                                                                 \
      /* update 1 */                                                           \
      _Pragma("unroll")                                                        \
      for (int u = 0; u < 2; ++u) {                                            \
        float r = __builtin_amdgcn_rcpf(                                       \
            1.f + __builtin_amdgcn_exp2f(fmaf(ra1[eb + u], -L2E, nbsr1)));     \
        float z = __builtin_amdgcn_rcpf(                                       \
            1.f + __builtin_amdgcn_exp2f(fmaf(za1[eb + u], -L2E, nbsz1)));     \
        float pre = fmaf(r, na1[eb + u] + bhn1, xa1[eb + u] + bin1);           \
        float e2 = __builtin_amdgcn_exp2f(pre * TWO_L2E);                      \
        float n = fmaf(-2.f, __builtin_amdgcn_rcpf(e2 + 1.f), 1.f);            \
        h1[u] = fmaf(z, h1[u] - n, n);                                         \
        lds16[(WBH) + woff1[u]] = (_Float16)h1[u];                             \
      }                                                                        \
    } else {                                                                   \
      PRIO(0);                                                                 \
      /* wave 7: only triple 0 update */                                       \
      _Pragma("unroll")                                                        \
      for (int u = 0; u < 2; ++u) {                                            \
        float r = __builtin_amdgcn_rcpf(                                       \
            1.f + __builtin_amdgcn_exp2f(fmaf(ra0[eb + u], -L2E, nbsr0)));     \
        float z = __builtin_amdgcn_rcpf(                                       \
            1.f + __builtin_amdgcn_exp2f(fmaf(za0[eb + u], -L2E, nbsz0)));     \
        float pre = fmaf(r, na0[eb + u] + bhn0, xa0[eb + u] + bin0);           \
        float e2 = __builtin_amdgcn_exp2f(pre * TWO_L2E);                      \
        float n = fmaf(-2.f, __builtin_amdgcn_rcpf(e2 + 1.f), 1.f);            \
        h0[u] = fmaf(z, h0[u] - n, n);                                         \
        lds16[(WBH) + woff0[u]] = (_Float16)h0[u];                             \
      }                                                                        \
    }                                                                          \
    __syncthreads();                                                           \
  } while (0)

  for (int tt = 0; tt < T; tt += 2) {
    GRU_STEP(0,      HBUF_H, pa7_e, a8i);        // even t: read buf0, write buf1
    GRU_STEP(HBUF_H, 0,      pa7_o, a8i + 128);  // odd  t: read buf1, write buf0
    pa7_e += inc7; pa7_o += inc7; a8i += 256;
  }
#undef GRU_STEP

#pragma unroll
  for (int u = 0; u < 2; ++u) {
    int row = rowb + u;
    if (j0 < H) out[(size_t)(blk * RPB + row) * H + j0] = h0[u];
    if (g1ok && j1 < H) out[(size_t)(blk * RPB + row) * H + j1] = h1[u];
  }
}

extern "C" void kernel_launch(void* const* d_in, const int* in_sizes, int n_in,
                              void* d_out, int out_size, void* d_ws, size_t ws_size,
                              hipStream_t stream) {
  const float* X      = (const float*)d_in[0];
  const float* conv_w = (const float*)d_in[1];
  const float* conv_b = (const float*)d_in[2];
  const float* w_ih   = (const float*)d_in[3];
  const float* w_hh   = (const float*)d_in[4];
  const float* b_ih   = (const float*)d_in[5];
  const float* b_hh   = (const float*)d_in[6];
  float* out = (float*)d_out;

  static bool attr_set = false;
  if (!attr_set) {
    hipFuncSetAttribute((const void*)st_gru_kernel,
                        hipFuncAttributeMaxDynamicSharedMemorySize, SMEM_BYTES);
    attr_set = true;
  }

  pack_w_kernel<<<dim3(NT2, NS), 64, 0, stream>>>(w_ih, w_hh);
  st_gru_kernel<<<NBLK, NTHR, SMEM_BYTES, stream>>>(X, conv_w, conv_b, b_ih, b_hh, out);
}

// Round 8
// 177.890 us; speedup vs baseline: 1.2549x; 1.2549x over previous
//
#include <hip/hip_runtime.h>

#define BATCH 2048
#define T     128
#define CIN   2
#define COUT  16
#define H     232
#define RPB   8                 // batch rows per block
#define NBLK  (BATCH/RPB)       // 256 blocks -> 1 per CU
#define NTHR  512               // 8 waves, 2/SIMD
#define NGRP  15                // j-groups of 16 (232 -> 240 padded)
#define NT2   48                // tiles: r=0..14, z=15..29, n=30..44, 45..47 zero pad
#define NS    9                 // K slices of 32
#define HROW  272               // h row stride in halves
#define HBUF_H (RPB * HROW)     // 2176 halves per ping-pong h buffer

// dynamic LDS carve (bytes)
#define OFF_HA   0
#define SZ_HA    (2 * RPB * HROW * 2)          // 8704: ping-pong fp16 h
#define OFF_XE   (OFF_HA + SZ_HA)
#define SZ_XE    (T * RPB * 16 * 2)            // 32768: conv output all t
#define OFF_WL   (OFF_XE + SZ_XE)
#define SZ_WL    (8 * 10 * 64 * 8 * 2)         // 81920: per-wave z s0-3 x2 + xn x2
#define OFF_CW   (OFF_WL + SZ_WL)
#define SZ_CW    512
#define SMEM_BYTES (OFF_CW + SZ_CW)            // 123904
#define OFF_XE_H (OFF_XE / 2)

#define L2E     1.4426950408889634f
#define TWO_L2E 2.8853900817779268f

typedef _Float16 half8 __attribute__((ext_vector_type(8)));
typedef float  floatx4 __attribute__((ext_vector_type(4)));

#define MFMA __builtin_amdgcn_mfma_f32_16x16x32_f16

// packed fp16 weights, fragment-contiguous: [tile][slice][lane][8]
__device__ __align__(16) _Float16 g_packedW[NT2 * NS * 64 * 8];

__global__ void pack_w_kernel(const float* __restrict__ w_ih,
                              const float* __restrict__ w_hh) {
  int tile = blockIdx.x, slice = blockIdx.y, lane = threadIdx.x;
  int grp = tile / NGRP;                       // 0=r,1=z,2=n (3=dummy)
  int j   = (tile % NGRP) * 16 + (lane & 15);
  int g   = grp * H + j;
  bool valid = (tile < 3 * NGRP) && (j < H);
  half8 v = {};
  if (valid) {
#pragma unroll
    for (int i = 0; i < 8; ++i) {
      int k = slice * 32 + ((lane >> 4) << 3) + i;
      float f = 0.f;
      if (slice < 8) {
        if (k < H) f = w_hh[g * H + k];
        else if (k < H + COUT && grp < 2) f = w_ih[g * COUT + (k - H)];
      } else {
        int xk = k - 256;
        if (xk >= 0 && xk < COUT && grp == 2) f = w_ih[g * COUT + xk];
      }
      v[i] = (_Float16)f;
    }
  }
  *(half8*)&g_packedW[((tile * NS + slice) * 64 + lane) * 8] = v;
}

__global__ __launch_bounds__(NTHR, 2) void st_gru_kernel(
    const float* __restrict__ X,
    const float* __restrict__ conv_w, const float* __restrict__ conv_b,
    const float* __restrict__ b_ih, const float* __restrict__ b_hh,
    float* __restrict__ out) {

  extern __shared__ __align__(16) char smem[];
  _Float16* lds16  = (_Float16*)smem;
  _Float16* hAflat = (_Float16*)(smem + OFF_HA);
  _Float16* Xemb   = (_Float16*)(smem + OFF_XE);
  _Float16* wLDS   = (_Float16*)(smem + OFF_WL);
  float*    cwp    = (float*)(smem + OFF_CW);

  const int tid  = threadIdx.x;
  const int lane = tid & 63;
  const int wave = tid >> 6;
  const int r_a  = lane & 15;   // A row / C col (gate j within group)
  const int ch4  = lane >> 4;   // k-chunk / C row group
  const int blk  = blockIdx.x;
  const int rr   = r_a & 7;     // batch row this lane reads (rows 8-15 duplicate 0-7)
  const int swz  = rr & 3;

  for (int i = tid; i < 2 * RPB * HROW; i += NTHR) hAflat[i] = (_Float16)0;
  if (tid < COUT * CIN * 3) cwp[tid] = conv_w[tid];
  if (tid < COUT) cwp[96 + tid] = conv_b[tid];
  __syncthreads();

  // ---- conv1d(2->16,k=3,pad=1)+ReLU for ALL t upfront -> Xemb (fp16)
  for (int p = tid; p < RPB * T; p += NTHR) {
    int r = p >> 7, t = p & (T - 1);
    const float* xr = X + (size_t)(blk * RPB + r) * (T * CIN);
    float x0[3], x1[3];
#pragma unroll
    for (int d = 0; d < 3; ++d) {
      int tt = t + d - 1;
      bool ok = (unsigned)tt < (unsigned)T;
      x0[d] = ok ? xr[tt * 2] : 0.f;
      x1[d] = ok ? xr[tt * 2 + 1] : 0.f;
    }
    half8 lo, hi;
#pragma unroll
    for (int c = 0; c < COUT; ++c) {
      float a = cwp[96 + c];
#pragma unroll
      for (int d = 0; d < 3; ++d)
        a += x0[d] * cwp[c * 6 + d] + x1[d] * cwp[c * 6 + 3 + d];
      _Float16 hv = (_Float16)fmaxf(a, 0.f);
      if (c < 8) lo[c] = hv; else hi[c - 8] = hv;
    }
    *(half8*)&Xemb[(t * RPB + r) * 16] = lo;
    *(half8*)&Xemb[(t * RPB + r) * 16 + 8] = hi;
  }

  // ---- per-wave tiles (2 gate-triples each)
  const int gi0 = wave * 2, gi1 = wave * 2 + 1;
  const bool g1ok = (gi1 < NGRP);
  const int tr0 = gi0, tz0 = gi0 + NGRP, tn0 = gi0 + 2 * NGRP;
  const int tr1 = g1ok ? gi1 : 45, tz1 = g1ok ? gi1 + NGRP : 46, tn1 = g1ok ? gi1 + 2 * NGRP : 47;
  const half8* Wp = (const half8*)g_packedW;

  // LDS-staged frags (10/wave): [0-3]=z0 s0-3, [4-7]=z1 s0-3, [8]=xn0, [9]=xn1
  half8* myz = (half8*)(wLDS + wave * (10 * 64 * 8));
#pragma unroll
  for (int f = 0; f < 4; ++f) myz[f * 64 + lane] = Wp[(tz0 * NS + f) * 64 + lane];
#pragma unroll
  for (int f = 0; f < 4; ++f) myz[(4 + f) * 64 + lane] = Wp[(tz1 * NS + f) * 64 + lane];
  myz[8 * 64 + lane] = Wp[(tn0 * NS + 8) * 64 + lane];
  myz[9 * 64 + lane] = Wp[(tn1 * NS + 8) * 64 + lane];

  // VGPR/AGPR-resident frags: r s0-7, n s0-7, z s4-7 (R4 config)
  half8 wr0[8], wr1[8], wn0[8], wn1[8], wzh0[4], wzh1[4];
#pragma unroll
  for (int s = 0; s < 8; ++s) {
    wr0[s] = Wp[(tr0 * NS + s) * 64 + lane];
    wr1[s] = Wp[(tr1 * NS + s) * 64 + lane];
    wn0[s] = Wp[(tn0 * NS + s) * 64 + lane];
    wn1[s] = Wp[(tn1 * NS + s) * 64 + lane];
  }
#pragma unroll
  for (int s = 0; s < 4; ++s) {
    wzh0[s] = Wp[(tz0 * NS + 4 + s) * 64 + lane];
    wzh1[s] = Wp[(tz1 * NS + 4 + s) * 64 + lane];
  }

  const int j0 = gi0 * 16 + r_a, j1 = gi1 * 16 + r_a;
  // pre-scaled biases for exp2-folded sigmoids
  float nbsr0 = 0.f, nbsz0 = 0.f, bin0 = 0.f, bhn0 = 0.f;
  float nbsr1 = 0.f, nbsz1 = 0.f, bin1 = 0.f, bhn1 = 0.f;
  if (j0 < H) {
    nbsr0 = -L2E * (b_ih[j0] + b_hh[j0]);
    nbsz0 = -L2E * (b_ih[H + j0] + b_hh[H + j0]);
    bin0 = b_ih[2 * H + j0]; bhn0 = b_hh[2 * H + j0];
  }
  if (g1ok && j1 < H) {
    nbsr1 = -L2E * (b_ih[j1] + b_hh[j1]);
    nbsz1 = -L2E * (b_ih[H + j1] + b_hh[H + j1]);
    bin1 = b_ih[2 * H + j1]; bhn1 = b_hh[2 * H + j1];
  }

  // all-lane update distribution: ch4 -> (elem base, row base)
  const int eb   = (ch4 & 2);
  const int rowb = ((ch4 & 1) << 2) | (ch4 & 2);

  int woff0[2], woff1[2];
#pragma unroll
  for (int u = 0; u < 2; ++u) {
    int row = rowb + u;
    woff0[u] = row * HROW + ((j0 & ~31) | ((((j0 >> 3) & 3) ^ (row & 3)) << 3) | (j0 & 7));
    woff1[u] = row * HROW + ((j1 & ~31) | ((((j1 >> 3) & 3) ^ (row & 3)) << 3) | (j1 & 7));
  }

  float h0[2] = {0.f, 0.f};
  float h1[2] = {0.f, 0.f};

  // loop-invariant LDS half-indices
  const int aoff = rr * HROW + ((ch4 ^ swz) << 3);
  const int inc7 = (ch4 == 0) ? 0 : 256;
  int pa7_e = (ch4 == 0) ? (0      + rr * HROW + 224 + (swz << 3))
                         : (OFF_XE_H + rr * 16 + ((ch4 == 2) ? 8 : 0));
  int pa7_o = (ch4 == 0) ? (HBUF_H + rr * HROW + 224 + (swz << 3))
                         : (OFF_XE_H + 128 + rr * 16 + ((ch4 == 2) ? 8 : 0));
  int a8i = OFF_XE_H + rr * 16 + ((ch4 & 1) << 3);

  __syncthreads();

  // R4 schedule + explicit 19-read ds burst + exp2 activations. No setprio/sched_barrier.
#define GRU_STEP(RBH, WBH, PA7, A8I) do {                                      \
    /* ---- ds_read burst: 9 A-frags + 10 weight frags ---- */                 \
    half8 A_[7];                                                               \
    _Pragma("unroll")                                                          \
    for (int s = 0; s < 7; ++s)                                                \
      A_[s] = *(const half8*)&lds16[(RBH) + aoff + s * 32];                    \
    half8 A7_ = *(const half8*)&lds16[(PA7)];                                  \
    half8 A8_ = *(const half8*)&lds16[(A8I)];                                  \
    half8 zf0_[4], zf1_[4], xf0_, xf1_;                                        \
    _Pragma("unroll")                                                          \
    for (int s = 0; s < 4; ++s) {                                              \
      zf0_[s] = myz[s * 64 + lane];                                            \
      zf1_[s] = myz[(4 + s) * 64 + lane];                                      \
    }                                                                          \
    xf0_ = myz[8 * 64 + lane];                                                 \
    xf1_ = myz[9 * 64 + lane];                                                 \
    /* ---- triple 0: 25 MFMAs (per-slice r,z,n) ---- */                       \
    floatx4 ra0 = {}, za0 = {}, na0 = {}, xa0 = {};                            \
    _Pragma("unroll")                                                          \
    for (int s = 0; s < 4; ++s) {                                              \
      ra0 = MFMA(A_[s], wr0[s], ra0, 0, 0, 0);                                 \
      za0 = MFMA(A_[s], zf0_[s], za0, 0, 0, 0);                                \
      na0 = MFMA(A_[s], wn0[s], na0, 0, 0, 0);                                 \
    }                                                                          \
    _Pragma("unroll")                                                          \
    for (int s = 4; s < 7; ++s) {                                              \
      ra0 = MFMA(A_[s], wr0[s], ra0, 0, 0, 0);                                 \
      za0 = MFMA(A_[s], wzh0[s - 4], za0, 0, 0, 0);                            \
      na0 = MFMA(A_[s], wn0[s], na0, 0, 0, 0);                                 \
    }                                                                          \
    ra0 = MFMA(A7_, wr0[7], ra0, 0, 0, 0);                                     \
    za0 = MFMA(A7_, wzh0[3], za0, 0, 0, 0);                                    \
    na0 = MFMA(A7_, wn0[7], na0, 0, 0, 0);                                     \
    xa0 = MFMA(A8_, xf0_, xa0, 0, 0, 0);                                       \
    /* ---- triple 1 s0-3 (12 MFMAs) ---- */                                   \
    floatx4 ra1 = {}, za1 = {}, na1 = {}, xa1 = {};                            \
    _Pragma("unroll")                                                          \
    for (int s = 0; s < 4; ++s) {                                              \
      ra1 = MFMA(A_[s], wr1[s], ra1, 0, 0, 0);                                 \
      za1 = MFMA(A_[s], zf1_[s], za1, 0, 0, 0);                                \
      na1 = MFMA(A_[s], wn1[s], na1, 0, 0, 0);                                 \
    }                                                                          \
    /* sigmoids of triple 0 (overlap triple-1 MFMA stream) */                  \
    float sr_[2], sz_[2];                                                      \
    _Pragma("unroll")                                                          \
    for (int u = 0; u < 2; ++u) {                                              \
      sr_[u] = __builtin_amdgcn_rcpf(                                          \
          1.f + __builtin_amdgcn_exp2f(fmaf(ra0[eb + u], -L2E, nbsr0)));       \
      sz_[u] = __builtin_amdgcn_rcpf(                                          \
          1.f + __builtin_amdgcn_exp2f(fmaf(za0[eb + u], -L2E, nbsz0)));       \
    }                                                                          \
    _Pragma("unroll")                                                          \
    for (int s = 4; s < 7; ++s) {                                              \
      ra1 = MFMA(A_[s], wr1[s], ra1, 0, 0, 0);                                 \
      za1 = MFMA(A_[s], wzh1[s - 4], za1, 0, 0, 0);                            \
      na1 = MFMA(A_[s], wn1[s], na1, 0, 0, 0);                                 \
    }                                                                          \
    /* update 0 (overlaps triple-1 tail) */                                    \
    _Pragma("unroll")                                                          \
    for (int u = 0; u < 2; ++u) {                                              \
      float pre = fmaf(sr_[u], na0[eb + u] + bhn0, xa0[eb + u] + bin0);        \
      float e2 = __builtin_amdgcn_exp2f(pre * TWO_L2E);                        \
      float n = fmaf(-2.f, __builtin_amdgcn_rcpf(e2 + 1.f), 1.f);              \
      h0[u] = fmaf(sz_[u], h0[u] - n, n);                                      \
      lds16[(WBH) + woff0[u]] = (_Float16)h0[u];                               \
    }                                                                          \
    ra1 = MFMA(A7_, wr1[7], ra1, 0, 0, 0);                                     \
    za1 = MFMA(A7_, wzh1[3], za1, 0, 0, 0);                                    \
    na1 = MFMA(A7_, wn1[7], na1, 0, 0, 0);                                     \
    xa1 = MFMA(A8_, xf1_, xa1, 0, 0, 0);                                       \
    /* update 1 */                                                             \
    _Pragma("unroll")                                                          \
    for (int u = 0; u < 2; ++u) {                                              \
      float r = __builtin_amdgcn_rcpf(                                         \
          1.f + __builtin_amdgcn_exp2f(fmaf(ra1[eb + u], -L2E, nbsr1)));       \
      float z = __builtin_amdgcn_rcpf(                                         \
          1.f + __builtin_amdgcn_exp2f(fmaf(za1[eb + u], -L2E, nbsz1)));       \
      float pre = fmaf(r, na1[eb + u] + bhn1, xa1[eb + u] + bin1);             \
      float e2 = __builtin_amdgcn_exp2f(pre * TWO_L2E);                        \
      float n = fmaf(-2.f, __builtin_amdgcn_rcpf(e2 + 1.f), 1.f);              \
      h1[u] = fmaf(z, h1[u] - n, n);                                           \
      lds16[(WBH) + woff1[u]] = (_Float16)h1[u];  /* wave7 -> pad slots (0) */ \
    }                                                                          \
    __syncthreads();                                                           \
  } while (0)

  for (int tt = 0; tt < T; tt += 2) {
    GRU_STEP(0,      HBUF_H, pa7_e, a8i);        // even t: read buf0, write buf1
    GRU_STEP(HBUF_H, 0,      pa7_o, a8i + 128);  // odd  t: read buf1, write buf0
    pa7_e += inc7; pa7_o += inc7; a8i += 256;
  }
#undef GRU_STEP

#pragma unroll
  for (int u = 0; u < 2; ++u) {
    int row = rowb + u;
    if (j0 < H) out[(size_t)(blk * RPB + row) * H + j0] = h0[u];
    if (g1ok && j1 < H) out[(size_t)(blk * RPB + row) * H + j1] = h1[u];
  }
}

extern "C" void kernel_launch(void* const* d_in, const int* in_sizes, int n_in,
                              void* d_out, int out_size, void* d_ws, size_t ws_size,
                              hipStream_t stream) {
  const float* X      = (const float*)d_in[0];
  const float* conv_w = (const float*)d_in[1];
  const float* conv_b = (const float*)d_in[2];
  const float* w_ih   = (const float*)d_in[3];
  const float* w_hh   = (const float*)d_in[4];
  const float* b_ih   = (const float*)d_in[5];
  const float* b_hh   = (const float*)d_in[6];
  float* out = (float*)d_out;

  static bool attr_set = false;
  if (!attr_set) {
    hipFuncSetAttribute((const void*)st_gru_kernel,
                        hipFuncAttributeMaxDynamicSharedMemorySize, SMEM_BYTES);
    attr_set = true;
  }

  pack_w_kernel<<<dim3(NT2, NS), 64, 0, stream>>>(w_ih, w_hh);
  st_gru_kernel<<<NBLK, NTHR, SMEM_BYTES, stream>>>(X, conv_w, conv_b, b_ih, b_hh, out);
}

// Round 9
// 173.288 us; speedup vs baseline: 1.2883x; 1.0266x over previous
//
#include <hip/hip_runtime.h>

#define BATCH 2048
#define T     128
#define CIN   2
#define COUT  16
#define H     232
#define RPB   8                 // batch rows per block
#define NBLK  (BATCH/RPB)       // 256 blocks -> 1 per CU
#define NTHR  512               // 8 waves, 2/SIMD
#define NGRP  15                // j-groups of 16 (232 -> 240 padded)
#define NT2   48                // tiles: r=0..14, z=15..29, n=30..44, 45..47 zero pad
#define NS    9                 // K slices of 32
#define HROW  272               // h row stride in halves
#define HBUF_H (RPB * HROW)     // 2176 halves per ping-pong h buffer

// dynamic LDS carve (bytes)
#define OFF_HA   0
#define SZ_HA    (2 * RPB * HROW * 2)          // 8704: ping-pong fp16 h
#define OFF_XE   (OFF_HA + SZ_HA)
#define SZ_XE    (T * RPB * 16 * 2)            // 32768: conv output all t
#define OFF_WL   (OFF_XE + SZ_XE)
#define SZ_WL    (8 * 4 * 64 * 8 * 2)          // 32768: per-wave z1 s0-3 only
#define OFF_CW   (OFF_WL + SZ_WL)
#define SZ_CW    512
#define SMEM_BYTES (OFF_CW + SZ_CW)            // 74752
#define OFF_XE_H (OFF_XE / 2)

#define L2E     1.4426950408889634f
#define TWO_L2E 2.8853900817779268f

typedef _Float16 half8 __attribute__((ext_vector_type(8)));
typedef float  floatx4 __attribute__((ext_vector_type(4)));

#define MFMA __builtin_amdgcn_mfma_f32_16x16x32_f16

// packed fp16 weights, fragment-contiguous: [tile][slice][lane][8]
__device__ __align__(16) _Float16 g_packedW[NT2 * NS * 64 * 8];

__global__ void pack_w_kernel(const float* __restrict__ w_ih,
                              const float* __restrict__ w_hh) {
  int tile = blockIdx.x, slice = blockIdx.y, lane = threadIdx.x;
  int grp = tile / NGRP;                       // 0=r,1=z,2=n (3=dummy)
  int j   = (tile % NGRP) * 16 + (lane & 15);
  int g   = grp * H + j;
  bool valid = (tile < 3 * NGRP) && (j < H);
  half8 v = {};
  if (valid) {
#pragma unroll
    for (int i = 0; i < 8; ++i) {
      int k = slice * 32 + ((lane >> 4) << 3) + i;
      float f = 0.f;
      if (slice < 8) {
        if (k < H) f = w_hh[g * H + k];
        else if (k < H + COUT && grp < 2) f = w_ih[g * COUT + (k - H)];
      } else {
        int xk = k - 256;
        if (xk >= 0 && xk < COUT && grp == 2) f = w_ih[g * COUT + xk];
      }
      v[i] = (_Float16)f;
    }
  }
  *(half8*)&g_packedW[((tile * NS + slice) * 64 + lane) * 8] = v;
}

__global__ __launch_bounds__(NTHR, 2) void st_gru_kernel(
    const float* __restrict__ X,
    const float* __restrict__ conv_w, const float* __restrict__ conv_b,
    const float* __restrict__ b_ih, const float* __restrict__ b_hh,
    float* __restrict__ out) {

  extern __shared__ __align__(16) char smem[];
  _Float16* lds16  = (_Float16*)smem;
  _Float16* hAflat = (_Float16*)(smem + OFF_HA);
  _Float16* Xemb   = (_Float16*)(smem + OFF_XE);
  _Float16* wLDS   = (_Float16*)(smem + OFF_WL);
  float*    cwp    = (float*)(smem + OFF_CW);

  const int tid  = threadIdx.x;
  const int lane = tid & 63;
  const int wave = tid >> 6;
  const int r_a  = lane & 15;   // A row / C col (gate j within group)
  const int ch4  = lane >> 4;   // k-chunk / C row group
  const int blk  = blockIdx.x;
  const int rr   = r_a & 7;     // batch row this lane reads (rows 8-15 duplicate 0-7)
  const int swz  = rr & 3;

  for (int i = tid; i < 2 * RPB * HROW; i += NTHR) hAflat[i] = (_Float16)0;
  if (tid < COUT * CIN * 3) cwp[tid] = conv_w[tid];
  if (tid < COUT) cwp[96 + tid] = conv_b[tid];
  __syncthreads();

  // ---- conv1d(2->16,k=3,pad=1)+ReLU for ALL t upfront -> Xemb (fp16)
  for (int p = tid; p < RPB * T; p += NTHR) {
    int r = p >> 7, t = p & (T - 1);
    const float* xr = X + (size_t)(blk * RPB + r) * (T * CIN);
    float x0[3], x1[3];
#pragma unroll
    for (int d = 0; d < 3; ++d) {
      int tt = t + d - 1;
      bool ok = (unsigned)tt < (unsigned)T;
      x0[d] = ok ? xr[tt * 2] : 0.f;
      x1[d] = ok ? xr[tt * 2 + 1] : 0.f;
    }
    half8 lo, hi;
#pragma unroll
    for (int c = 0; c < COUT; ++c) {
      float a = cwp[96 + c];
#pragma unroll
      for (int d = 0; d < 3; ++d)
        a += x0[d] * cwp[c * 6 + d] + x1[d] * cwp[c * 6 + 3 + d];
      _Float16 hv = (_Float16)fmaxf(a, 0.f);
      if (c < 8) lo[c] = hv; else hi[c - 8] = hv;
    }
    *(half8*)&Xemb[(t * RPB + r) * 16] = lo;
    *(half8*)&Xemb[(t * RPB + r) * 16 + 8] = hi;
  }

  // ---- per-wave tiles (2 gate-triples each)
  const int gi0 = wave * 2, gi1 = wave * 2 + 1;
  const bool g1ok = (gi1 < NGRP);
  const int tr0 = gi0, tz0 = gi0 + NGRP, tn0 = gi0 + 2 * NGRP;
  const int tr1 = g1ok ? gi1 : 45, tz1 = g1ok ? gi1 + NGRP : 46, tn1 = g1ok ? gi1 + 2 * NGRP : 47;
  const half8* Wp = (const half8*)g_packedW;

  // LDS-staged frags (4/wave): z1 s0-3 only
  half8* myz = (half8*)(wLDS + wave * (4 * 64 * 8));
#pragma unroll
  for (int f = 0; f < 4; ++f) myz[f * 64 + lane] = Wp[(tz1 * NS + f) * 64 + lane];

  // Register-resident frags: r s0-7 x2, n s0-7 x2, z0 s0-7, z1 s4-7, xn x2
  half8 wr0[8], wr1[8], wn0[8], wn1[8], wzf0[4], wzh0[4], wzh1[4], xf0r, xf1r;
#pragma unroll
  for (int s = 0; s < 8; ++s) {
    wr0[s] = Wp[(tr0 * NS + s) * 64 + lane];
    wr1[s] = Wp[(tr1 * NS + s) * 64 + lane];
    wn0[s] = Wp[(tn0 * NS + s) * 64 + lane];
    wn1[s] = Wp[(tn1 * NS + s) * 64 + lane];
  }
#pragma unroll
  for (int s = 0; s < 4; ++s) {
    wzf0[s] = Wp[(tz0 * NS + s) * 64 + lane];
    wzh0[s] = Wp[(tz0 * NS + 4 + s) * 64 + lane];
    wzh1[s] = Wp[(tz1 * NS + 4 + s) * 64 + lane];
  }
  xf0r = Wp[(tn0 * NS + 8) * 64 + lane];
  xf1r = Wp[(tn1 * NS + 8) * 64 + lane];

  const int j0 = gi0 * 16 + r_a, j1 = gi1 * 16 + r_a;
  // pre-scaled biases for exp2-folded sigmoids
  float nbsr0 = 0.f, nbsz0 = 0.f, bin0 = 0.f, bhn0 = 0.f;
  float nbsr1 = 0.f, nbsz1 = 0.f, bin1 = 0.f, bhn1 = 0.f;
  if (j0 < H) {
    nbsr0 = -L2E * (b_ih[j0] + b_hh[j0]);
    nbsz0 = -L2E * (b_ih[H + j0] + b_hh[H + j0]);
    bin0 = b_ih[2 * H + j0]; bhn0 = b_hh[2 * H + j0];
  }
  if (g1ok && j1 < H) {
    nbsr1 = -L2E * (b_ih[j1] + b_hh[j1]);
    nbsz1 = -L2E * (b_ih[H + j1] + b_hh[H + j1]);
    bin1 = b_ih[2 * H + j1]; bhn1 = b_hh[2 * H + j1];
  }

  // all-lane update distribution: ch4 -> (elem base, row base)
  const int eb   = (ch4 & 2);
  const int rowb = ((ch4 & 1) << 2) | (ch4 & 2);

  int woff0[2], woff1[2];
#pragma unroll
  for (int u = 0; u < 2; ++u) {
    int row = rowb + u;
    woff0[u] = row * HROW + ((j0 & ~31) | ((((j0 >> 3) & 3) ^ (row & 3)) << 3) | (j0 & 7));
    woff1[u] = row * HROW + ((j1 & ~31) | ((((j1 >> 3) & 3) ^ (row & 3)) << 3) | (j1 & 7));
  }

  float h0[2] = {0.f, 0.f};
  float h1[2] = {0.f, 0.f};

  // loop-invariant LDS half-indices
  const int aoff = rr * HROW + ((ch4 ^ swz) << 3);
  const int inc7 = (ch4 == 0) ? 0 : 256;
  int pa7_e = (ch4 == 0) ? (0      + rr * HROW + 224 + (swz << 3))
                         : (OFF_XE_H + rr * 16 + ((ch4 == 2) ? 8 : 0));
  int pa7_o = (ch4 == 0) ? (HBUF_H + rr * HROW + 224 + (swz << 3))
                         : (OFF_XE_H + 128 + rr * 16 + ((ch4 == 2) ? 8 : 0));
  int a8i = OFF_XE_H + rr * 16 + ((ch4 & 1) << 3);

  __syncthreads();

  // R8 schedule; weight frags mostly register-resident (only z1 s0-3 from LDS).
#define GRU_STEP(RBH, WBH, PA7, A8I) do {                                      \
    /* ---- ds_read burst: 9 A-frags + 4 z1 frags ---- */                      \
    half8 A_[7];                                                               \
    _Pragma("unroll")                                                          \
    for (int s = 0; s < 7; ++s)                                                \
      A_[s] = *(const half8*)&lds16[(RBH) + aoff + s * 32];                    \
    half8 A7_ = *(const half8*)&lds16[(PA7)];                                  \
    half8 A8_ = *(const half8*)&lds16[(A8I)];                                  \
    half8 zf1_[4];                                                             \
    _Pragma("unroll")                                                          \
    for (int s = 0; s < 4; ++s)                                                \
      zf1_[s] = myz[s * 64 + lane];                                            \
    /* ---- triple 0: 25 MFMAs (per-slice r,z,n) ---- */                       \
    floatx4 ra0 = {}, za0 = {}, na0 = {}, xa0 = {};                            \
    _Pragma("unroll")                                                          \
    for (int s = 0; s < 4; ++s) {                                              \
      ra0 = MFMA(A_[s], wr0[s], ra0, 0, 0, 0);                                 \
      za0 = MFMA(A_[s], wzf0[s], za0, 0, 0, 0);                                \
      na0 = MFMA(A_[s], wn0[s], na0, 0, 0, 0);                                 \
    }                                                                          \
    _Pragma("unroll")                                                          \
    for (int s = 4; s < 7; ++s) {                                              \
      ra0 = MFMA(A_[s], wr0[s], ra0, 0, 0, 0);                                 \
      za0 = MFMA(A_[s], wzh0[s - 4], za0, 0, 0, 0);                            \
      na0 = MFMA(A_[s], wn0[s], na0, 0, 0, 0);                                 \
    }                                                                          \
    ra0 = MFMA(A7_, wr0[7], ra0, 0, 0, 0);                                     \
    za0 = MFMA(A7_, wzh0[3], za0, 0, 0, 0);                                    \
    na0 = MFMA(A7_, wn0[7], na0, 0, 0, 0);                                     \
    xa0 = MFMA(A8_, xf0r, xa0, 0, 0, 0);                                       \
    /* ---- triple 1 s0-3 (12 MFMAs) ---- */                                   \
    floatx4 ra1 = {}, za1 = {}, na1 = {}, xa1 = {};                            \
    _Pragma("unroll")                                                          \
    for (int s = 0; s < 4; ++s) {                                              \
      ra1 = MFMA(A_[s], wr1[s], ra1, 0, 0, 0);                                 \
      za1 = MFMA(A_[s], zf1_[s], za1, 0, 0, 0);                                \
      na1 = MFMA(A_[s], wn1[s], na1, 0, 0, 0);                                 \
    }                                                                          \
    /* sigmoids of triple 0 (overlap triple-1 MFMA stream) */                  \
    float sr_[2], sz_[2];                                                      \
    _Pragma("unroll")                                                          \
    for (int u = 0; u < 2; ++u) {                                              \
      sr_[u] = __builtin_amdgcn_rcpf(                                          \
          1.f + __builtin_amdgcn_exp2f(fmaf(ra0[eb + u], -L2E, nbsr0)));       \
      sz_[u] = __builtin_amdgcn_rcpf(                                          \
          1.f + __builtin_amdgcn_exp2f(fmaf(za0[eb + u], -L2E, nbsz0)));       \
    }                                                                          \
    _Pragma("unroll")                                                          \
    for (int s = 4; s < 7; ++s) {                                              \
      ra1 = MFMA(A_[s], wr1[s], ra1, 0, 0, 0);                                 \
      za1 = MFMA(A_[s], wzh1[s - 4], za1, 0, 0, 0);                            \
      na1 = MFMA(A_[s], wn1[s], na1, 0, 0, 0);                                 \
    }                                                                          \
    /* update 0 (overlaps triple-1 tail) */                                    \
    _Pragma("unroll")                                                          \
    for (int u = 0; u < 2; ++u) {                                              \
      float pre = fmaf(sr_[u], na0[eb + u] + bhn0, xa0[eb + u] + bin0);        \
      float e2 = __builtin_amdgcn_exp2f(pre * TWO_L2E);                        \
      float n = fmaf(-2.f, __builtin_amdgcn_rcpf(e2 + 1.f), 1.f);              \
      h0[u] = fmaf(sz_[u], h0[u] - n, n);                                      \
      lds16[(WBH) + woff0[u]] = (_Float16)h0[u];                               \
    }                                                                          \
    ra1 = MFMA(A7_, wr1[7], ra1, 0, 0, 0);                                     \
    za1 = MFMA(A7_, wzh1[3], za1, 0, 0, 0);                                    \
    na1 = MFMA(A7_, wn1[7], na1, 0, 0, 0);                                     \
    xa1 = MFMA(A8_, xf1r, xa1, 0, 0, 0);                                       \
    /* update 1 */                                                             \
    _Pragma("unroll")                                                          \
    for (int u = 0; u < 2; ++u) {                                              \
      float r = __builtin_amdgcn_rcpf(                                         \
          1.f + __builtin_amdgcn_exp2f(fmaf(ra1[eb + u], -L2E, nbsr1)));       \
      float z = __builtin_amdgcn_rcpf(                                         \
          1.f + __builtin_amdgcn_exp2f(fmaf(za1[eb + u], -L2E, nbsz1)));       \
      float pre = fmaf(r, na1[eb + u] + bhn1, xa1[eb + u] + bin1);             \
      float e2 = __builtin_amdgcn_exp2f(pre * TWO_L2E);                        \
      float n = fmaf(-2.f, __builtin_amdgcn_rcpf(e2 + 1.f), 1.f);              \
      h1[u] = fmaf(z, h1[u] - n, n);                                           \
      lds16[(WBH) + woff1[u]] = (_Float16)h1[u];  /* wave7 -> pad slots (0) */ \
    }                                                                          \
    __syncthreads();                                                           \
  } while (0)

  for (int tt = 0; tt < T; tt += 2) {
    GRU_STEP(0,      HBUF_H, pa7_e, a8i);        // even t: read buf0, write buf1
    GRU_STEP(HBUF_H, 0,      pa7_o, a8i + 128);  // odd  t: read buf1, write buf0
    pa7_e += inc7; pa7_o += inc7; a8i += 256;
  }
#undef GRU_STEP

#pragma unroll
  for (int u = 0; u < 2; ++u) {
    int row = rowb + u;
    if (j0 < H) out[(size_t)(blk * RPB + row) * H + j0] = h0[u];
    if (g1ok && j1 < H) out[(size_t)(blk * RPB + row) * H + j1] = h1[u];
  }
}

extern "C" void kernel_launch(void* const* d_in, const int* in_sizes, int n_in,
                              void* d_out, int out_size, void* d_ws, size_t ws_size,
                              hipStream_t stream) {
  const float* X      = (const float*)d_in[0];
  const float* conv_w = (const float*)d_in[1];
  const float* conv_b = (const float*)d_in[2];
  const float* w_ih   = (const float*)d_in[3];
  const float* w_hh   = (const float*)d_in[4];
  const float* b_ih   = (const float*)d_in[5];
  const float* b_hh   = (const float*)d_in[6];
  float* out = (float*)d_out;

  static bool attr_set = false;
  if (!attr_set) {
    hipFuncSetAttribute((const void*)st_gru_kernel,
                        hipFuncAttributeMaxDynamicSharedMemorySize, SMEM_BYTES);
    attr_set = true;
  }

  pack_w_kernel<<<dim3(NT2, NS), 64, 0, stream>>>(w_ih, w_hh);
  st_gru_kernel<<<NBLK, NTHR, SMEM_BYTES, stream>>>(X, conv_w, conv_b, b_ih, b_hh, out);
}